// Round 11
// baseline (86.907 us; speedup 1.0000x reference)
//
#include <hip/hip_runtime.h>
#include <hip/hip_bf16.h>

#define BATCH 8
#define NDIM 2048
#define FDIM 256
#define CH 32   // row-chunks for column-sum partials (64 rows each)

typedef float f32x4 __attribute__((ext_vector_type(4)));
typedef short bf16x8 __attribute__((ext_vector_type(8)));
typedef short bf16x4 __attribute__((ext_vector_type(4)));

// hardware RNE convert (lowers to v_cvt_pk_bf16_f32 when paired)
__device__ __forceinline__ short f2bf(float f) {
  __hip_bfloat16 h = __float2bfloat16(f);
  short s;
  __builtin_memcpy(&s, &h, 2);
  return s;
}

__device__ __forceinline__ void gload_lds16(const void* g, void* l) {
  __builtin_amdgcn_global_load_lds(
      (const __attribute__((address_space(1))) void*)g,
      (__attribute__((address_space(3))) void*)l, 16, 0, 0);
}

// ---- Kernel 1: partial column sums of adj ----
__global__ __launch_bounds__(256) void k_colsum(const float* __restrict__ adj,
                                                float* __restrict__ part) {
  int bid = blockIdx.x;
  int cb = bid & 1;
  int ch = (bid >> 1) & (CH - 1);
  int b = bid >> 6;
  int col = cb * 1024 + threadIdx.x * 4;
  const float* p = adj + (size_t)b * NDIM * NDIM + (size_t)(ch * 64) * NDIM + col;
  f32x4 acc = {0.f, 0.f, 0.f, 0.f};
#pragma unroll 8
  for (int i = 0; i < 64; ++i) acc += *(const f32x4*)(p + (size_t)i * NDIM);
  *(f32x4*)(part + (size_t)(b * CH + ch) * NDIM + col) = acc;
}

// ---- Kernel 2 (merged): blocks 0..63 -> d = rsqrt(colsum); 64..79 -> Wt ----
__global__ __launch_bounds__(256) void k_small(const float* __restrict__ part,
                                               float* __restrict__ dnorm,
                                               const float* __restrict__ w,
                                               short* __restrict__ wt) {
  int t = threadIdx.x;
  if (blockIdx.x < 64) {
    int idx = blockIdx.x * 256 + t;  // b*NDIM + j
    int b = idx >> 11, j = idx & (NDIM - 1);
    float s = 0.f;
#pragma unroll
    for (int c = 0; c < CH; ++c) s += part[(size_t)(b * CH + c) * NDIM + j];
    dnorm[idx] = rsqrtf(s);
  } else {
    __shared__ float tile[64][65];
    int bb = blockIdx.x - 64;
    int bx = bb & 3, by = bb >> 2;
    int f0 = by * 64, o0 = bx * 64;
    int c4 = 4 * (t & 15);
#pragma unroll
    for (int q = 0; q < 4; ++q) {
      int r = (t >> 4) + 16 * q;
      f32x4 v = *(const f32x4*)(w + (size_t)(f0 + r) * FDIM + o0 + c4);
#pragma unroll
      for (int i = 0; i < 4; ++i) tile[r][c4 + i] = v[i];
    }
    __syncthreads();
#pragma unroll
    for (int q = 0; q < 4; ++q) {
      int r = (t >> 4) + 16 * q;
      bf16x4 pk;
#pragma unroll
      for (int i = 0; i < 4; ++i) pk[i] = f2bf(tile[c4 + i][r]);
      *(bf16x4*)(wt + (size_t)(o0 + r) * FDIM + f0 + c4) = pk;
    }
  }
}

// ---- Kernel 3: St[b][o][m] = bf16(d[b][m] * (X @ W)[m][o]) ----
__global__ __launch_bounds__(256) void k_support(const float* __restrict__ in,
                                                 const short* __restrict__ wt,
                                                 const float* __restrict__ dnorm,
                                                 short* __restrict__ st) {
  __shared__ short Al[64 * 32];
  __shared__ short Bl[256 * 32];
  int t = threadIdx.x, lane = t & 63, w = t >> 6;
  int b = blockIdx.x >> 5;
  int m0 = (blockIdx.x & 31) * 64;
  const float* inb = in + ((size_t)b * NDIM + m0) * FDIM;

  f32x4 acc[4][4];
#pragma unroll
  for (int m = 0; m < 4; ++m)
#pragma unroll
    for (int n = 0; n < 4; ++n) acc[m][n] = {0.f, 0.f, 0.f, 0.f};

  int ar = t >> 2, ac = t & 3;
  for (int it = 0; it < 8; ++it) {
    int k0 = it * 32;
    {
      f32x4 v0 = *(const f32x4*)(inb + (size_t)ar * FDIM + k0 + 8 * ac);
      f32x4 v1 = *(const f32x4*)(inb + (size_t)ar * FDIM + k0 + 8 * ac + 4);
      bf16x8 p;
#pragma unroll
      for (int i = 0; i < 4; ++i) { p[i] = f2bf(v0[i]); p[4 + i] = f2bf(v1[i]); }
      *(bf16x8*)&Al[ar * 32 + 8 * ac] = p;
    }
#pragma unroll
    for (int i = 0; i < 4; ++i) {
      int ss = i * 256 + t;
      int o = ss >> 2, c = ss & 3;
      gload_lds16(wt + (size_t)o * FDIM + k0 + 8 * c, &Bl[ss * 8]);
    }
    __syncthreads();
    bf16x8 af[4], bf[4];
#pragma unroll
    for (int m = 0; m < 4; ++m)
      af[m] = *(const bf16x8*)&Al[(16 * m + (lane & 15)) * 32 + (lane >> 4) * 8];
#pragma unroll
    for (int n = 0; n < 4; ++n)
      bf[n] = *(const bf16x8*)&Bl[(64 * w + 16 * n + (lane & 15)) * 32 + (lane >> 4) * 8];
#pragma unroll
    for (int m = 0; m < 4; ++m)
#pragma unroll
      for (int n = 0; n < 4; ++n)
        acc[m][n] = __builtin_amdgcn_mfma_f32_16x16x32_bf16(af[m], bf[n], acc[m][n], 0, 0, 0);
    __syncthreads();
  }
#pragma unroll
  for (int m = 0; m < 4; ++m) {
    int row = m0 + 16 * m + ((lane >> 4) << 2);
    float dm[4];
#pragma unroll
    for (int j = 0; j < 4; ++j) dm[j] = dnorm[b * NDIM + row + j];
#pragma unroll
    for (int n = 0; n < 4; ++n) {
      int col = 64 * w + 16 * n + (lane & 15);
      bf16x4 pk;
#pragma unroll
      for (int j = 0; j < 4; ++j) pk[j] = f2bf(acc[m][n][j] * dm[j]);
      *(bf16x4*)(st + ((size_t)(b * FDIM + col)) * NDIM + row) = pk;
    }
  }
}

// ---- Kernel 4: out = d_n * (adj @ St^T) + bias ----
// 256 blocks x 512 threads (8 waves, 2Mx4N), BM=64, BN=256, BK=64.
// R9's proven two-barrier double-buffer skeleton. A path: reg-staged with
// DEPTH-2 registers (aNext loaded one body early -> cvt hits landed data),
// cvt_pk + swizzled bf16 ds_write in the stage phase. B: global_load_lds.
// vmcnt(6) keeps {4 B-glls, 2 A-loads} in flight across both barriers.
// LDS 2 x (8 + 32) KB = 80 KB.
__global__ __launch_bounds__(512) void k_main(const float* __restrict__ adj,
                                              const short* __restrict__ st,
                                              const float* __restrict__ dnorm,
                                              const float* __restrict__ bias,
                                              float* __restrict__ out) {
  __shared__ short Albf[2][64 * 64];  // 2 x 8 KB  (bf16 A tiles)
  __shared__ short Bl[2][256 * 64];   // 2 x 32 KB (bf16 B tiles)
  int t = threadIdx.x, lane = t & 63, w = t >> 6;
  int wm = w & 1, wn = w >> 1;
  int b = blockIdx.x & 7;              // batch <-> XCD
  int n0 = (blockIdx.x >> 3) * 64;     // M row-tile
  const float* ab = adj + ((size_t)b * NDIM + n0) * NDIM;
  const short* stb = st + (size_t)b * FDIM * NDIM;

  // A reg-staging: thread t -> row=t>>3, 8-f32 segment seg=t&7.
  int arow = t >> 3, aseg = t & 7;
  const float* aSrc = ab + (size_t)arow * NDIM + aseg * 8;
  int adst = arow * 64 + ((aseg ^ (arow & 7)) * 8);  // swizzled bf16 index
  // B gll staging: 4 slots/thread, source chunk pre-swizzled (c ^= row&7)
  const short* bS[4];
#pragma unroll
  for (int i = 0; i < 4; ++i) {
    int s = i * 512 + t;
    int row = s >> 3, c = (s & 7) ^ (row & 7);
    bS[i] = stb + (size_t)row * NDIM + c * 8;
  }

  f32x4 acc[2][4];
#pragma unroll
  for (int m = 0; m < 2; ++m)
#pragma unroll
    for (int n = 0; n < 4; ++n) acc[m][n] = {0.f, 0.f, 0.f, 0.f};

  int lr = lane & 15, kg = lane >> 4, sw = lane & 7;

  // prologue: A(t0) regs -> glls(t0) -> A(t1) regs issued -> cvt+write A(t0)
  f32x4 aCur0 = *(const f32x4*)(aSrc);
  f32x4 aCur1 = *(const f32x4*)(aSrc + 4);
#pragma unroll
  for (int i = 0; i < 4; ++i) gload_lds16(bS[i], &Bl[0][(i * 512 + t) * 8]);
  f32x4 aNext0 = *(const f32x4*)(aSrc + 64);
  f32x4 aNext1 = *(const f32x4*)(aSrc + 64 + 4);
  {
    bf16x8 ap;
#pragma unroll
    for (int j = 0; j < 4; ++j) { ap[j] = f2bf(aCur0[j]); ap[4 + j] = f2bf(aCur1[j]); }
    *(bf16x8*)&Albf[0][adst] = ap;
  }

  for (int it = 0; it < 32; ++it) {
    int cur = it & 1, nxt = cur ^ 1;
    if (it < 31) {
      // stage tile it+1 into nxt
      size_t ko = (size_t)(it + 1) * 64;
#pragma unroll
      for (int i = 0; i < 4; ++i)
        gload_lds16(bS[i] + ko, &Bl[nxt][(i * 512 + t) * 8]);
      bf16x8 ap;  // cvt waits aNext loads -> FIFO also drains glls(tile it)
#pragma unroll
      for (int j = 0; j < 4; ++j) { ap[j] = f2bf(aNext0[j]); ap[4 + j] = f2bf(aNext1[j]); }
      *(bf16x8*)&Albf[nxt][adst] = ap;
      if (it < 30) {
        size_t ko2 = (size_t)(it + 2) * 64;
        aNext0 = *(const f32x4*)(aSrc + ko2);
        aNext1 = *(const f32x4*)(aSrc + ko2 + 4);
      }
      asm volatile("s_waitcnt vmcnt(6)" ::: "memory");
    } else {
      asm volatile("s_waitcnt vmcnt(0)" ::: "memory");
    }
    asm volatile("s_waitcnt lgkmcnt(0)" ::: "memory");
    __builtin_amdgcn_s_barrier();   // BARRIER 1: tile `cur` fully staged
    asm volatile("" ::: "memory");
    __builtin_amdgcn_sched_barrier(0);
#pragma unroll
    for (int h = 0; h < 2; ++h) {
      int gsw = ((h * 4 + kg) ^ sw) * 8;
      bf16x8 af0 = *(const bf16x8*)&Albf[cur][(wm * 32 + lr) * 64 + gsw];
      bf16x8 af1 = *(const bf16x8*)&Albf[cur][(wm * 32 + 16 + lr) * 64 + gsw];
      bf16x8 bv0 = *(const bf16x8*)&Bl[cur][(wn * 64 + lr) * 64 + gsw];
      bf16x8 bv1 = *(const bf16x8*)&Bl[cur][(wn * 64 + 16 + lr) * 64 + gsw];
      bf16x8 bv2 = *(const bf16x8*)&Bl[cur][(wn * 64 + 32 + lr) * 64 + gsw];
      bf16x8 bv3 = *(const bf16x8*)&Bl[cur][(wn * 64 + 48 + lr) * 64 + gsw];
      acc[0][0] = __builtin_amdgcn_mfma_f32_16x16x32_bf16(af0, bv0, acc[0][0], 0, 0, 0);
      acc[0][1] = __builtin_amdgcn_mfma_f32_16x16x32_bf16(af0, bv1, acc[0][1], 0, 0, 0);
      acc[0][2] = __builtin_amdgcn_mfma_f32_16x16x32_bf16(af0, bv2, acc[0][2], 0, 0, 0);
      acc[0][3] = __builtin_amdgcn_mfma_f32_16x16x32_bf16(af0, bv3, acc[0][3], 0, 0, 0);
      acc[1][0] = __builtin_amdgcn_mfma_f32_16x16x32_bf16(af1, bv0, acc[1][0], 0, 0, 0);
      acc[1][1] = __builtin_amdgcn_mfma_f32_16x16x32_bf16(af1, bv1, acc[1][1], 0, 0, 0);
      acc[1][2] = __builtin_amdgcn_mfma_f32_16x16x32_bf16(af1, bv2, acc[1][2], 0, 0, 0);
      acc[1][3] = __builtin_amdgcn_mfma_f32_16x16x32_bf16(af1, bv3, acc[1][3], 0, 0, 0);
    }
    asm volatile("s_waitcnt lgkmcnt(0)" ::: "memory");
    __builtin_amdgcn_s_barrier();   // BARRIER 2: cur reads done
    asm volatile("" ::: "memory");
  }

  // epilogue: out[b][row][col] = d_n[row]*acc + bias[col]
#pragma unroll
  for (int mf = 0; mf < 2; ++mf) {
    int row = n0 + wm * 32 + mf * 16 + kg * 4;
    f32x4 dr = *(const f32x4*)&dnorm[b * NDIM + row];
#pragma unroll
    for (int nf = 0; nf < 4; ++nf) {
      int col = wn * 64 + nf * 16 + lr;
      float bv = bias[col];
      float* op = out + ((size_t)b * NDIM + row) * FDIM + col;
#pragma unroll
      for (int j = 0; j < 4; ++j) op[(size_t)j * FDIM] = dr[j] * acc[mf][nf][j] + bv;
    }
  }
}

extern "C" void kernel_launch(void* const* d_in, const int* in_sizes, int n_in,
                              void* d_out, int out_size, void* d_ws, size_t ws_size,
                              hipStream_t stream) {
  (void)in_sizes; (void)n_in; (void)out_size; (void)ws_size;
  const float* input = (const float*)d_in[0];
  const float* adj = (const float*)d_in[1];
  const float* weight = (const float*)d_in[2];
  const float* bias = (const float*)d_in[3];
  float* out = (float*)d_out;

  char* ws = (char*)d_ws;
  short* st = (short*)ws;                                       // 8 MB  (bf16 S^T)
  float* dnorm = (float*)(ws + 8ull * 1024 * 1024);             // 64 KB
  float* part = (float*)(ws + 8ull * 1024 * 1024 + 65536);      // 2 MB
  short* wt = (short*)(ws + 8ull * 1024 * 1024 + 65536 + 2ull * 1024 * 1024);  // 128 KB

  k_colsum<<<dim3(BATCH * CH * 2), dim3(256), 0, stream>>>(adj, part);
  k_small<<<dim3(80), dim3(256), 0, stream>>>(part, dnorm, weight, wt);
  k_support<<<dim3(BATCH * (NDIM / 64)), dim3(256), 0, stream>>>(input, wt, dnorm, st);
  k_main<<<dim3(BATCH * (NDIM / 64)), dim3(512), 0, stream>>>(adj, st, dnorm, bias, out);
}